// Round 12
// baseline (30.894 us; speedup 1.0000x reference)
//
#include <hip/hip_runtime.h>
#include <float.h>

typedef float v2f __attribute__((ext_vector_type(2)));

#define BATCH   8
#define NPTS    4096
#define THREADS 512
#define NWAVE   (THREADS / 64)            // 8 waves
#define XTILE   512                       // x-points per block
#define P       8                         // x-points per lane
#define NH      2                         // y halves per (dir,b,tile)
#define YH      (NPTS / NH)               // 2048 y per block
#define NPAIRB  (YH / 2)                  // 1024 staged y-pairs
#define PPW     (NPAIRB / NWAVE)          // 128 pairs per wave
#define NSLOT   (2 * BATCH * NPTS)        // 65536 x-slots
#define TOTAL_BLOCKS (2 * BATCH * (NPTS / XTILE) * NH)   // 2*8*8*2 = 256

__device__ __forceinline__ float min3f(float a, float b, float c) {
    float d;
    asm("v_min3_f32 %0, %1, %2, %3" : "=v"(d) : "v"(a), "v"(b), "v"(c));
    return d;
}
// genuine VOP3P packed fma (r4/r11's builtin lowered to 2x v_fma_f32)
__device__ __forceinline__ v2f pk_fma(v2f a, v2f b, v2f c) {
    v2f d;
    asm("v_pk_fma_f32 %0, %1, %2, %3" : "=v"(d) : "v"(a), "v"(b), "v"(c));
    return d;
}

union F4V2 { float4 f; v2f v[2]; };

// r11's proven math (absmax 0) with the two pipes halved together:
//  - real v_pk_fma_f32: 3 pk_fma + 1 min3 per y-pair per x  -> 2.0 VALU/pair
//  - P=8 x per lane: 1 ds_read_b128 per 512 pair-instances  -> 2048 b128/CU
// Block = (dir, b, x-tile of 512, y-half of 2048). Lane owns x {l+64p, p<8}.
// LDS pair-packed: ysAB[k]=(-2y0[2k],-2y0[2k+1],-2y1[2k],-2y1[2k+1]),
//                  ysCW[k]=(-2y2[2k],-2y2[2k+1],|y[2k]|^2,|y[2k+1]|^2).
// |x|^2 folded after the 8-wave min (min is translation-invariant).
__global__ __launch_bounds__(THREADS) void chamfer_min_kernel(
    const float* __restrict__ A, const float* __restrict__ Bp,
    float* __restrict__ partial)
{
    __shared__ float4 ysAB[NPAIRB + 2];      // 32 KB (+pad for prefetch)
    __shared__ float4 ysCW[NPAIRB + 2];
    __shared__ float  smin[NWAVE][XTILE];    // 16 KB
    __shared__ float  sxs[XTILE];            // 2 KB

    const int bid  = blockIdx.x;
    const int q    = bid & 1;                // y-half
    const int tile = (bid >> 1) & 7;
    const int b    = (bid >> 4) & 7;
    const int dir  = (bid >> 7) & 1;
    const int tid  = threadIdx.x;
    const int lane = tid & 63;
    const int wave = tid >> 6;

    const float* xbase = (dir == 0 ? A : Bp) + (size_t)b * NPTS * 3;
    const float* ybase = (dir == 0 ? Bp : A) + (size_t)b * NPTS * 3
                         + (size_t)q * YH * 3;

    // ---- stage y-half: thread t handles points 4t..4t+3 = 3 aligned float4 ----
    {
        const float4* yg4 = (const float4*)ybase;
        const float4 f0 = yg4[3 * tid + 0];
        const float4 f1 = yg4[3 * tid + 1];
        const float4 f2 = yg4[3 * tid + 2];
        // p0=(f0.x,f0.y,f0.z) p1=(f0.w,f1.x,f1.y) p2=(f1.z,f1.w,f2.x) p3=(f2.y,f2.z,f2.w)
        const int k0 = 2 * tid;
        ysAB[k0]     = make_float4(-2.f * f0.x, -2.f * f0.w, -2.f * f0.y, -2.f * f1.x);
        ysCW[k0]     = make_float4(-2.f * f0.z, -2.f * f1.y,
                                   f0.x * f0.x + f0.y * f0.y + f0.z * f0.z,
                                   f0.w * f0.w + f1.x * f1.x + f1.y * f1.y);
        ysAB[k0 + 1] = make_float4(-2.f * f1.z, -2.f * f2.y, -2.f * f1.w, -2.f * f2.z);
        ysCW[k0 + 1] = make_float4(-2.f * f2.x, -2.f * f2.w,
                                   f1.z * f1.z + f1.w * f1.w + f2.x * f2.x,
                                   f2.y * f2.y + f2.z * f2.z + f2.w * f2.w);
    }

    // ---- 8 x-points per lane, splatted for packed math ----
    v2f X0[P], X1[P], X2[P];
    float mn[P];
    #pragma unroll
    for (int p = 0; p < P; ++p) {
        const int xi = tile * XTILE + p * 64 + lane;
        const float x0 = xbase[xi * 3 + 0];
        const float x1 = xbase[xi * 3 + 1];
        const float x2 = xbase[xi * 3 + 2];
        X0[p] = (v2f){x0, x0};
        X1[p] = (v2f){x1, x1};
        X2[p] = (v2f){x2, x2};
        mn[p] = FLT_MAX;
        if (wave == 0)
            sxs[p * 64 + lane] = x0 * x0 + x1 * x1 + x2 * x2;
    }
    __syncthreads();

    // ---- main loop: wave scans its 128 y-pairs, next-iter LDS prefetch ----
    const float4* abp = &ysAB[wave * PPW];
    const float4* cwp = &ysCW[wave * PPW];
    F4V2 ab, cw;
    ab.f = abp[0];
    cw.f = cwp[0];
    #pragma unroll 4
    for (int k = 0; k < PPW; ++k) {
        F4V2 abn, cwn;
        abn.f = abp[k + 1];                  // pad entry on last iter (unused)
        cwn.f = cwp[k + 1];
        const v2f Av = ab.v[0], Bv = ab.v[1];
        const v2f Cv = cw.v[0], Wv = cw.v[1];
        #pragma unroll
        for (int p = 0; p < P; ++p) {
            const v2f d = pk_fma(X0[p], Av, pk_fma(X1[p], Bv, pk_fma(X2[p], Cv, Wv)));
            mn[p] = min3f(mn[p], d[0], d[1]);
        }
        ab = abn;
        cw = cwn;
    }

    #pragma unroll
    for (int p = 0; p < P; ++p)
        smin[wave][p * 64 + lane] = mn[p];
    __syncthreads();

    // ---- per-x half-partial: 8-way min, add |x|^2, clamp, write ws[g][q] ----
    {
        float m = smin[0][tid];
        #pragma unroll
        for (int w = 1; w < NWAVE; ++w) m = fminf(m, smin[w][tid]);
        const int g = ((dir * BATCH + b) << 12) + tile * XTILE + tid;
        partial[g * NH + q] = fmaxf(sxs[tid] + m, 0.0f);
    }
}

// Stage 2: 64 blocks x 256 threads, 4 x-slots/thread: min over the 2 y-halves,
// sum within block (fixed-order tree) -> part2[64].
__global__ __launch_bounds__(256) void chamfer_reduce1(
    const float2* __restrict__ pw, float* __restrict__ part2)
{
    __shared__ float r[256];
    const int tid = threadIdx.x;
    float acc = 0.0f;
    #pragma unroll
    for (int j = 0; j < 4; ++j) {
        const float2 v = pw[blockIdx.x * 1024 + j * 256 + tid];
        acc += fminf(v.x, v.y);
    }
    r[tid] = acc;
    __syncthreads();
    #pragma unroll
    for (int s = 128; s > 0; s >>= 1) {
        if (tid < s) r[tid] += r[tid + s];
        __syncthreads();
    }
    if (tid == 0) part2[blockIdx.x] = r[0];
}

// Stage 3: single wave, fixed-order reduce of 64 partials, scale, write scalar.
__global__ __launch_bounds__(64) void chamfer_reduce2(
    const float* __restrict__ part2, float* __restrict__ out)
{
    float v = part2[threadIdx.x];
    #pragma unroll
    for (int off = 32; off > 0; off >>= 1)
        v += __shfl_down(v, off, 64);
    if (threadIdx.x == 0) out[0] = v * (1.0f / (BATCH * NPTS));
}

extern "C" void kernel_launch(void* const* d_in, const int* in_sizes, int n_in,
                              void* d_out, int out_size, void* d_ws, size_t ws_size,
                              hipStream_t stream) {
    const float* A = (const float*)d_in[0];   // coor_recon [8,4096,3]
    const float* B = (const float*)d_in[1];   // pc_gd      [8,4096,3]
    float* partial = (float*)d_ws;            // [65536][2] half-partials (512 KB)
    float* part2   = partial + (size_t)NSLOT * NH;   // [64]
    float* out = (float*)d_out;

    chamfer_min_kernel<<<TOTAL_BLOCKS, THREADS, 0, stream>>>(A, B, partial);
    chamfer_reduce1<<<64, 256, 0, stream>>>((const float2*)partial, part2);
    chamfer_reduce2<<<1, 64, 0, stream>>>(part2, out);
}